// Round 8
// baseline (258.539 us; speedup 1.0000x reference)
//
#include <hip/hip_runtime.h>

#define Bdim 64
#define Tdim 2048
#define Fdim 256
#define TAIL 256      // truncated EMA window: 0.8^256 ~ 1e-25, far below fp32 noise
#define NCH 8
#define CHT 32        // TAIL / NCH

#define NCHUNK 8      // Fdim / 32 (BK=32)

typedef __bf16 bf16x8 __attribute__((ext_vector_type(8)));
typedef float f32x4 __attribute__((ext_vector_type(4)));

__device__ __forceinline__ unsigned short bf16_rne(float f) {
  unsigned int u = __float_as_uint(f);
  u += 0x7FFFu + ((u >> 16) & 1u);
  return (unsigned short)(u >> 16);
}

// async global->LDS, 16B per lane, dest = wave-uniform base + lane*16
__device__ __forceinline__ void gll16(const float* g, float* l) {
  __builtin_amdgcn_global_load_lds(
      (const __attribute__((address_space(1))) void*)g,
      (__attribute__((address_space(3))) void*)l, 16, 0, 0);
}

// prep:
//  blocks [0,256):  W fp32 -> Wf bf16 in 16x16 B-fragment order:
//    o = (c*16 + nt)*512 + lane*8 + e  holds bf16(W[k][n]) with
//    n = nt*16 + (lane&15),  k = c*32 + (lane>>4)*8 + e.
//  blocks [256,768): EMA partial sums over t-chunks (verified since R0).
__global__ void prep(const float* __restrict__ x, const float* __restrict__ W,
                     unsigned short* __restrict__ Wf, float* __restrict__ part) {
  const int blk = blockIdx.x;
  const int tid = threadIdx.x;
  if (blk < Fdim) {
    int o = blk * 256 + tid;
    int e = o & 7, lane = (o >> 3) & 63, nt = (o >> 9) & 15, c = o >> 13;
    int n = nt * 16 + (lane & 15);
    int k = c * 32 + (lane >> 4) * 8 + e;
    Wf[o] = bf16_rne(W[k * Fdim + n]);
  } else {
    int j = blk - Fdim;                // 0..511
    int b = j & 63, c = j >> 6;
    int f = tid;
    int t0 = Tdim - TAIL + c * CHT;
    float w = 0.2f * exp2f((float)(Tdim - 1 - t0) * -0.32192809488736235f);
    const float* xp = x + ((size_t)b * Tdim + t0) * Fdim + f;
    float s = 0.f;
#pragma unroll
    for (int q = 0; q < CHT; ++q) {
      s += w * xp[(size_t)q * Fdim];
      w *= 1.25f;
    }
    part[(c * Bdim + b) * Fdim + f] = s;
  }
}

// out[row][n] = sum_k x[row][k]*W[k][n] + bias[n] + lastref[b][n]
// T3/T4-min: global_load_lds staging + raw s_barrier + COUNTED vmcnt (never 0).
//  block = 32 rows x 256 cols, 4 waves; wave w: all 32 rows x cols [w*64, w*64+64).
//  A: fp32, 4-buffer LDS ring, prefetch depth 3. One gll (dwordx4) per thread per
//     chunk; wave w stages rows w*8..w*8+7. LDS dest linear (HW requirement);
//     SOURCE col-piece pre-swizzled p^=(row&7) so swizzled ds_read_b128 hits the
//     b128 bank floor (row stride 128B would otherwise serialize).
//  cvt fp32->bf16 at fragment-read time (native casts -> v_cvt_pk_bf16_f32).
//  B: 16x16-fragment stream from Wf (L2-hot), double-buffered in regs.
//  MFMA 16x16x32 (acc = 8 x f32x4 = 32 AGPR) -> ~96 regs -> 5 waves/SIMD.
//  Sync: per chunk ONE {vmcnt(8); s_barrier} pair. Issue-order proof: at chunk c's
//  barrier, >=8 VMEM ops are younger than gll(c+1) for every c (exactly 8 at c=6),
//  so vmcnt(8) guarantees gll(c+1) landed while gll(c+2),gll(c+3),B(c+1) fly on.
__global__ __launch_bounds__(256, 5)
void gemm_fused(const float* __restrict__ x, const unsigned short* __restrict__ Wf,
                const float* __restrict__ bias, const float* __restrict__ part,
                float* __restrict__ out) {
  __shared__ float Abuf[4][32 * 32];   // 4 ring buffers x 4 KB
  __shared__ float lref[Fdim];         // 1 KB -> 17408 B total

  const int tid = threadIdx.x;
  const int blk = blockIdx.x;          // 0..4095
  const int b = blk >> 6;              // batch (64 row-tiles of 32 per batch)
  const size_t row0 = (size_t)blk * 32;
  const int w = tid >> 6;
  const int lane = tid & 63;
  const int l15 = lane & 15;
  const int g = lane >> 4;             // k-granule group 0..3
  const int q0 = (2 * g) ^ (lane & 7); // swizzled 16B piece for fragment reads

  {  // lastref[b][n] + bias[n] (drained by the syncthreads below)
    float s = bias[tid];
#pragma unroll
    for (int c = 0; c < NCH; ++c) s += part[(c * Bdim + b) * Fdim + tid];
    lref[tid] = s;
  }
  __syncthreads();

  // gll: lane covers row w*8 + (lane>>3), source piece (lane&7)^(row&7)
  const int srow = (lane >> 3);        // 0..7 within wave's 8-row slab
  const float* gsrc =
      x + (row0 + w * 8 + srow) * Fdim + (((lane & 7) ^ srow) << 2);
  // B fragment stream: frag (c, nt=w*4+ntl) at bx + (c*16 + nt)*512
  const unsigned short* bx = Wf + (size_t)(w * 4) * 512 + lane * 8;

  f32x4 acc[2][4] = {};                // [m-tile][n-tile], 16x16 each
  bf16x8 Bf[2][4];                     // [chunk parity][n-tile]

  // ---- prologue: gll chunks 0..2, B chunk 0; vmcnt(6) => gll(0) landed ----
  gll16(gsrc + 0 * 32, &Abuf[0][w * 256]);
  gll16(gsrc + 1 * 32, &Abuf[1][w * 256]);
  gll16(gsrc + 2 * 32, &Abuf[2][w * 256]);
#pragma unroll
  for (int ntl = 0; ntl < 4; ++ntl)
    Bf[0][ntl] = *(const bf16x8*)(bx + (size_t)(0 * 16 + ntl) * 512);
  asm volatile("s_waitcnt vmcnt(6)" ::: "memory");
  __builtin_amdgcn_s_barrier();

  // ---- main loop: fully unrolled, counted-vmcnt pipeline ----
#pragma unroll
  for (int c = 0; c < NCHUNK; ++c) {
    if (c + 1 < NCHUNK) {              // B(c+1) -> other parity
#pragma unroll
      for (int ntl = 0; ntl < 4; ++ntl)
        Bf[(c + 1) & 1][ntl] =
            *(const bf16x8*)(bx + (size_t)((c + 1) * 16 + ntl) * 512);
    }
    if (c + 3 < NCHUNK)                // ring prefetch (buf (c+3)&3 was read at c-1)
      gll16(gsrc + (c + 3) * 32, &Abuf[(c + 3) & 3][w * 256]);

    // A fragments (chunk c): two 16B swizzled reads per m-tile, cvt to bf16
    bf16x8 a[2];
#pragma unroll
    for (int m = 0; m < 2; ++m) {
      const float* lp = &Abuf[c & 3][(m * 16 + l15) * 32];
      f32x4 lo = *(const f32x4*)(lp + q0 * 4);          // k = g*8 + 0..3
      f32x4 hi = *(const f32x4*)(lp + (q0 ^ 1) * 4);    // k = g*8 + 4..7
      bf16x8 af;
      af[0] = (__bf16)lo[0]; af[1] = (__bf16)lo[1];
      af[2] = (__bf16)lo[2]; af[3] = (__bf16)lo[3];
      af[4] = (__bf16)hi[0]; af[5] = (__bf16)hi[1];
      af[6] = (__bf16)hi[2]; af[7] = (__bf16)hi[3];
      a[m] = af;
    }
#pragma unroll
    for (int m = 0; m < 2; ++m)
#pragma unroll
      for (int ntl = 0; ntl < 4; ++ntl)
        acc[m][ntl] = __builtin_amdgcn_mfma_f32_16x16x32_bf16(
            a[m], Bf[c & 1][ntl], acc[m][ntl], 0, 0, 0);

    if (c + 1 < NCHUNK) {              // counted wait: gll(c+1) done, pipeline lives
      asm volatile("s_waitcnt vmcnt(8)" ::: "memory");
      __builtin_amdgcn_s_barrier();
    }
  }

  // epilogue: 16x16 C/D layout col=lane&15, row=(lane>>4)*4+reg  [m89/m91]
  float* op = out + row0 * Fdim;
  const int r4 = g * 4;
#pragma unroll
  for (int m = 0; m < 2; ++m) {
#pragma unroll
    for (int ntl = 0; ntl < 4; ++ntl) {
      const int col = w * 64 + ntl * 16 + l15;
      const float lb = lref[col];
#pragma unroll
      for (int r = 0; r < 4; ++r)
        op[(size_t)(m * 16 + r4 + r) * Fdim + col] = acc[m][ntl][r] + lb;
    }
  }
}

extern "C" void kernel_launch(void* const* d_in, const int* in_sizes, int n_in,
                              void* d_out, int out_size, void* d_ws, size_t ws_size,
                              hipStream_t stream) {
  const float* x = (const float*)d_in[0];
  const float* W = (const float*)d_in[1];
  const float* bias = (const float*)d_in[2];
  float* out = (float*)d_out;

  unsigned short* Wf = (unsigned short*)d_ws;                      // 128 KB
  float* part = (float*)((char*)d_ws + 131072);                    // 512 KB

  prep<<<Fdim + Bdim * NCH, 256, 0, stream>>>(x, W, Wf, part);
  gemm_fused<<<(Bdim * Tdim) / 32, 256, 0, stream>>>(x, Wf, bias, part, out);
}

// Round 9
// 245.858 us; speedup vs baseline: 1.0516x; 1.0516x over previous
//
#include <hip/hip_runtime.h>

#define Bdim 64
#define Tdim 2048
#define Fdim 256
#define TAIL 256      // truncated EMA window: 0.8^256 ~ 1e-25, far below fp32 noise
#define NCH 8
#define CHT 32        // TAIL / NCH

#define NCHUNK 8      // Fdim / 32
#define FR_STR 520    // fragment stride in ushorts: 1024B + 16B pad

typedef __bf16 bf16x8 __attribute__((ext_vector_type(8)));
typedef float f32x16 __attribute__((ext_vector_type(16)));
typedef unsigned short u16x8 __attribute__((ext_vector_type(8)));

__device__ __forceinline__ unsigned short bf16_rne(float f) {
  unsigned int u = __float_as_uint(f);
  u += 0x7FFFu + ((u >> 16) & 1u);
  return (unsigned short)(u >> 16);
}

// prep (verified since R3/R5):
//  blocks [0,256):  W fp32 -> Wf bf16 in B-fragment order:
//    o=(w4*32+c*4+s*2+which)*512+lane*8+e holds bf16(W[k][n]),
//    n=w4*64+which*32+(lane&31), k=c*32+(2*s+(lane>>5))*8+e.
//  blocks [256,768): EMA partial sums over t-chunks.
__global__ void prep(const float* __restrict__ x, const float* __restrict__ W,
                     unsigned short* __restrict__ Wf, float* __restrict__ part) {
  const int blk = blockIdx.x;
  const int tid = threadIdx.x;
  if (blk < Fdim) {
    int o = blk * 256 + tid;
    int e = o & 7, lane = (o >> 3) & 63, wh = (o >> 9) & 1, s = (o >> 10) & 1;
    int c = (o >> 11) & 7, w = o >> 14;
    int n = w * 64 + wh * 32 + (lane & 31);
    int k = c * 32 + (2 * s + (lane >> 5)) * 8 + e;
    Wf[o] = bf16_rne(W[k * Fdim + n]);
  } else {
    int j = blk - Fdim;                // 0..511
    int b = j & 63, c = j >> 6;
    int f = tid;
    int t0 = Tdim - TAIL + c * CHT;
    float w = 0.2f * exp2f((float)(Tdim - 1 - t0) * -0.32192809488736235f);
    const float* xp = x + ((size_t)b * Tdim + t0) * Fdim + f;
    float s = 0.f;
#pragma unroll
    for (int q = 0; q < CHT; ++q) {
      s += w * xp[(size_t)q * Fdim];
      w *= 1.25f;
    }
    part[(c * Bdim + b) * Fdim + f] = s;
  }
}

// out[row][n] = sum_k x[row][k]*W[k][n] + bias[n] + lastref[b][n]
// TALL-TILE GEMM: block = 128 rows x 256 cols, 8 waves; wave w owns 128 rows x
// 32 cols (one output column per lane) => B-stream bytes == out bytes (was 2-4x).
//  A: whole 128x256 tile staged ONCE upfront (two 8-deep coalesced bursts),
//     fp32->bf16, fragment-ordered LDS (R5-verified map, 4 m-subtiles),
//     involution swizzle wpos=dl^((dl>>5)<<2) on write and read. ONE barrier.
//  B: frag stream from Wf (L2-hot), refill-after-use, 2-chunk lead.
//  lref: single register per lane (fixed col) — no LDS, no extra barrier.
//  acc[4] f32x16 = 64 AGPR; ~110 VGPR total -> __launch_bounds__(512,4),
//  2 blocks/CU (LDS 65 KB).
__global__ __launch_bounds__(512, 4)
void gemm_fused(const float* __restrict__ x, const unsigned short* __restrict__ Wf,
                const float* __restrict__ bias, const float* __restrict__ part,
                float* __restrict__ out) {
  __shared__ unsigned short Afrag[64 * FR_STR];   // 64 frags x 1040B = 66560 B

  const int tid = threadIdx.x;
  const int blk = blockIdx.x;            // 0..1023
  const int b = blk >> 4;                // 16 row-tiles of 128 per batch
  const size_t row0 = (size_t)blk * 128;

  const int wave = tid >> 6;             // 0..7: n-slice of 32 cols
  const int lane = tid & 63;
  const int lm = lane & 31;
  const int half = lane >> 5;
  const int w4 = wave >> 1;              // Wf n-slice of 64
  const int wh = wave & 1;               // which 32-col half

  // per-lane lastref + bias for this lane's single output column
  const int ncol = wave * 32 + lm;
  float lr = bias[ncol];
#pragma unroll
  for (int c = 0; c < NCH; ++c) lr += part[(c * Bdim + b) * Fdim + ncol];

  // ---- A staging: thread -> row r=tid>>2 (0..127), q=tid&3 ----
  // granule g=p*4+q covers cols g*8..g*8+7; frag f=(c=p, i=r>>5, s=q>>1),
  // dest lane dl = (q&1)*32 + (r&31), swizzled pos wpos = dl^((dl>>5)<<2).
  const int r = tid >> 2, q = tid & 3;
  const int iw = r >> 5, sq = q >> 1, hb = q & 1;
  const int dl = hb * 32 + (r & 31);
  const int wpos = dl ^ ((dl >> 5) << 2);
  const float* ap = x + (row0 + r) * Fdim + q * 8;

#pragma unroll
  for (int h = 0; h < 2; ++h) {          // two bursts of 8 dwordx4 (32 VGPR peak)
    float4 av[4][2];
#pragma unroll
    for (int p4 = 0; p4 < 4; ++p4) {
      const int p = h * 4 + p4;
      av[p4][0] = *(const float4*)(ap + p * 32);
      av[p4][1] = *(const float4*)(ap + p * 32 + 4);
    }
#pragma unroll
    for (int p4 = 0; p4 < 4; ++p4) {
      const int p = h * 4 + p4;
      float4 v0 = av[p4][0], v1 = av[p4][1];
      u16x8 w;
      w[0] = bf16_rne(v0.x); w[1] = bf16_rne(v0.y);
      w[2] = bf16_rne(v0.z); w[3] = bf16_rne(v0.w);
      w[4] = bf16_rne(v1.x); w[5] = bf16_rne(v1.y);
      w[6] = bf16_rne(v1.z); w[7] = bf16_rne(v1.w);
      const int fragidx = (p * 4 + iw) * 2 + sq;
      *(u16x8*)&Afrag[fragidx * FR_STR + wpos * 8] = w;
    }
  }
  __syncthreads();                       // the ONLY barrier

  // ---- K-loop: barrier-free, fully unrolled ----
  const unsigned short* bx = Wf + (size_t)w4 * (32 * 512) + lane * 8;
#define BOFF(c, s) ((size_t)((c) * 4 + (s) * 2 + wh) * 512)

  const int rpos = lane ^ ((lane >> 5) << 2);
  const unsigned short* abase = &Afrag[rpos * 8];

  f32x16 acc[4] = {};                    // 4 m-subtiles of 32x32 (64 AGPR)
  bf16x8 Bf[2][2];                       // [chunk parity][s]

#pragma unroll
  for (int cc = 0; cc < 2; ++cc)         // B chunks 0,1 in flight
#pragma unroll
    for (int s = 0; s < 2; ++s)
      Bf[cc][s] = *(const bf16x8*)(bx + BOFF(cc, s));

#pragma unroll
  for (int c = 0; c < NCHUNK; ++c) {
    const int par = c & 1;
#pragma unroll
    for (int s = 0; s < 2; ++s) {
      bf16x8 a0 = *(const bf16x8*)&abase[((c * 4 + 0) * 2 + s) * FR_STR];
      bf16x8 a1 = *(const bf16x8*)&abase[((c * 4 + 1) * 2 + s) * FR_STR];
      bf16x8 a2 = *(const bf16x8*)&abase[((c * 4 + 2) * 2 + s) * FR_STR];
      bf16x8 a3 = *(const bf16x8*)&abase[((c * 4 + 3) * 2 + s) * FR_STR];
      acc[0] = __builtin_amdgcn_mfma_f32_32x32x16_bf16(a0, Bf[par][s], acc[0], 0, 0, 0);
      acc[1] = __builtin_amdgcn_mfma_f32_32x32x16_bf16(a1, Bf[par][s], acc[1], 0, 0, 0);
      acc[2] = __builtin_amdgcn_mfma_f32_32x32x16_bf16(a2, Bf[par][s], acc[2], 0, 0, 0);
      acc[3] = __builtin_amdgcn_mfma_f32_32x32x16_bf16(a3, Bf[par][s], acc[3], 0, 0, 0);
    }
    if (c + 2 < NCHUNK) {                // refill freed parity with chunk c+2
#pragma unroll
      for (int s = 0; s < 2; ++s)
        Bf[par][s] = *(const bf16x8*)(bx + BOFF(c + 2, s));
    }
  }
#undef BOFF

  // epilogue: C/D layout col=lane&31, row=(rr&3)+8*(rr>>2)+4*(lane>>5) [m74/m101]
  // each store instr: 2 x 128B segments (32 cols x 2 row-groups)
  float* op = out + row0 * Fdim + ncol;
  const int rbase = 4 * half;
#pragma unroll
  for (int i = 0; i < 4; ++i) {
#pragma unroll
    for (int rr = 0; rr < 16; ++rr) {
      const int rowi = i * 32 + (rr & 3) + 8 * (rr >> 2) + rbase;
      op[(size_t)rowi * Fdim] = acc[i][rr] + lr;
    }
  }
}

extern "C" void kernel_launch(void* const* d_in, const int* in_sizes, int n_in,
                              void* d_out, int out_size, void* d_ws, size_t ws_size,
                              hipStream_t stream) {
  const float* x = (const float*)d_in[0];
  const float* W = (const float*)d_in[1];
  const float* bias = (const float*)d_in[2];
  float* out = (float*)d_out;

  unsigned short* Wf = (unsigned short*)d_ws;                      // 128 KB
  float* part = (float*)((char*)d_ws + 131072);                    // 512 KB

  prep<<<Fdim + Bdim * NCH, 256, 0, stream>>>(x, W, Wf, part);
  gemm_fused<<<(Bdim * Tdim) / 128, 512, 0, stream>>>(x, Wf, bias, part, out);
}